// Round 6
// baseline (235.562 us; speedup 1.0000x reference)
//
#include <hip/hip_runtime.h>
#include <stdint.h>

#pragma clang fp contract(off)

#define BB 32
#define NN 200000
#define N4 50000
#define KK 500
#define KEEPN 100
#define CONF 0.05f
#define NMSTHR 0.5f
#define SLICES 8
#define SLICE_F4 6250          // float4 per slice (25000 elems)
#define LBINS 8192
#define LSHIFT 19              // top 13 bits of ordkey
#define LOCAL_CAP 2048
#define OUT_CAP 576
#define TMPCAP 640
#define OK0 0xBF733333u        // ordkey(0.95f) — fast-path candidate gate
#define FITER 9                // ceil(4608 / 512)
#define TAG 0x5AB00000u        // cnts publish tag (count in low 10 bits)
#define TAGMASK 0xFFFFFC00u

typedef unsigned long long u64;

// ---- workspace layout (bytes) ----
// 0       : cand 32*8*576*8 = 1179648
// 1179648 : cnts 256*4 = 1024  (tagged by producers, zeroed by consumers each call)

__device__ __forceinline__ unsigned int ordkey(float s) {
    unsigned int u = __float_as_uint(s);
    return (u & 0x80000000u) ? ~u : (u | 0x80000000u);
}

// wave-aggregated LDS append: one shared-counter atomic per wave, ordered scatter
__device__ __forceinline__ void wappend(bool pred, u64 key, u64* keys, int* lcnt, int lane) {
    u64 bm = __ballot(pred);
    int pre = __popcll(bm & ((1ULL << lane) - 1ULL));
    int tt  = __popcll(bm);
    int base = 0;
    if (lane == 0 && tt > 0) base = atomicAdd(lcnt, tt);
    base = __shfl(base, 0);
    if (pred) { int pos = base + pre; if (pos < LOCAL_CAP) keys[pos] = key; }
}

// ---- fused: per-slice select (256 blocks) -> tag handshake -> per-batch final
//      (32 blocks, x==0). 256 blocks <= 256 CUs: at most 32 spinners, 224 free
//      CUs for producers -> no scheduling deadlock possible. ----
__global__ __launch_bounds__(512) void fused_kernel(const float4* __restrict__ ps4,
                                                    const float* __restrict__ pboxes,
                                                    const int* __restrict__ plabels,
                                                    u64* cand,
                                                    unsigned int* cnts,
                                                    float* __restrict__ out) {
    // 53888 B phase-overlaid LDS pool:
    // select: hist[8192]u32 @0 | keys[2048]u64 @32768 | h256[256]u32 @49152
    // final : fhist[4096]u32 @0 | pfx[4096]u32 @16384 | tmp[640]u64 @32768
    //         msk[8][512]u64 @0 (after fhist/pfx dead)
    //         sboxes @37888 | sscore @47888 | slabel @49888 | clist @51888
    __shared__ u64 smem[6736];
    __shared__ int scnt[SLICES];
    __shared__ int soff[SLICES + 1];
    __shared__ u64 wmin[8], wmax[8];
    __shared__ unsigned int wsum[8], wmaxh[8];
    __shared__ float wred[8];
    __shared__ int ccnt[21], coff[22], cfill[21];
    __shared__ u64 validw[8], sremv[8], s_km;
    __shared__ int kept[KEEPN];
    __shared__ u64 s_kmn, s_kmx, s_prefix;
    __shared__ unsigned int s_region, s_cntgt, s_t13;
    __shared__ int s_lcnt, s_sc, s_shift0, s_shift, s_thrbin, s_selupper, s_fb, s_bsh, s_nk, s_stop;
    __shared__ float s_maxc;

    const int x = blockIdx.x, b = blockIdx.y;
    const int tid = threadIdx.x, lane = tid & 63, wv = tid >> 6;   // 8 waves

    // ======================= SELECT phase (all 256 blocks) =======================
    {
        unsigned int* hist = (unsigned int*)smem;
        u64* keys = (u64*)((char*)smem + 32768);
        unsigned int* h256 = (unsigned int*)((char*)smem + 49152);
        const float4* p = ps4 + (size_t)b * N4 + (size_t)x * SLICE_F4;
        const int ebase = x * (SLICE_F4 * 4);

        if (tid == 0) s_lcnt = 0;
        __syncthreads();

        // fast path: gate + wave-aggregated compact, single read of the slice
        for (int i = tid; i < SLICE_F4; i += 512) {
            float4 v = p[i];
            int n = ebase + (i << 2);
            unsigned int ux = ordkey(v.x), uy = ordkey(v.y);
            unsigned int uz = ordkey(v.z), uw = ordkey(v.w);
            wappend(ux >= OK0, ((u64)ux << 32) | (unsigned int)(~(unsigned int)(n)),     keys, &s_lcnt, lane);
            wappend(uy >= OK0, ((u64)uy << 32) | (unsigned int)(~(unsigned int)(n + 1)), keys, &s_lcnt, lane);
            wappend(uz >= OK0, ((u64)uz << 32) | (unsigned int)(~(unsigned int)(n + 2)), keys, &s_lcnt, lane);
            wappend(uw >= OK0, ((u64)uw << 32) | (unsigned int)(~(unsigned int)(n + 3)), keys, &s_lcnt, lane);
        }
        __syncthreads();
        int m = s_lcnt;

        if (m < KK || m > LOCAL_CAP) {
            // exact fallback: two-pass 13-bit histogram (512-thread port)
            for (int i = tid; i < LBINS; i += 512) hist[i] = 0;
            __syncthreads();
            for (int i = tid; i < SLICE_F4; i += 512) {
                float4 v = p[i];
                atomicAdd(&hist[ordkey(v.x) >> LSHIFT], 1u);
                atomicAdd(&hist[ordkey(v.y) >> LSHIFT], 1u);
                atomicAdd(&hist[ordkey(v.z) >> LSHIFT], 1u);
                atomicAdd(&hist[ordkey(v.w) >> LSHIFT], 1u);
            }
            __syncthreads();
            unsigned int v16[16], tot = 0;
            for (int j = 0; j < 16; ++j) { v16[j] = hist[tid * 16 + j]; tot += v16[j]; }
            unsigned int sfx = tot;
            for (int off = 1; off < 64; off <<= 1) {
                unsigned int t2 = __shfl_down(sfx, off);
                sfx += (lane + off < 64) ? t2 : 0u;
            }
            if (lane == 0) wsum[wv] = sfx;
            __syncthreads();
            unsigned int wafter = 0;
            for (int w2 = wv + 1; w2 < 8; ++w2) wafter += wsum[w2];
            unsigned int sn = wafter + (sfx - tot);
            for (int j = 15; j >= 0; --j) {
                unsigned int s = sn + v16[j];
                if (s >= (unsigned)KK && sn < (unsigned)KK) s_t13 = (unsigned)(tid * 16 + j);
                sn = s;
            }
            if (tid == 0) s_lcnt = 0;
            __syncthreads();
            const unsigned int t13 = s_t13;
            for (int i = tid; i < SLICE_F4; i += 512) {
                float4 v = p[i];
                int n = ebase + (i << 2);
                unsigned int u;
                u = ordkey(v.x); if ((u >> LSHIFT) >= t13) { int pos = atomicAdd(&s_lcnt, 1);
                    if (pos < LOCAL_CAP) keys[pos] = ((u64)u << 32) | (unsigned int)(~(unsigned int)(n)); }
                u = ordkey(v.y); if ((u >> LSHIFT) >= t13) { int pos = atomicAdd(&s_lcnt, 1);
                    if (pos < LOCAL_CAP) keys[pos] = ((u64)u << 32) | (unsigned int)(~(unsigned int)(n + 1)); }
                u = ordkey(v.z); if ((u >> LSHIFT) >= t13) { int pos = atomicAdd(&s_lcnt, 1);
                    if (pos < LOCAL_CAP) keys[pos] = ((u64)u << 32) | (unsigned int)(~(unsigned int)(n + 2)); }
                u = ordkey(v.w); if ((u >> LSHIFT) >= t13) { int pos = atomicAdd(&s_lcnt, 1);
                    if (pos < LOCAL_CAP) keys[pos] = ((u64)u << 32) | (unsigned int)(~(unsigned int)(n + 3)); }
            }
            __syncthreads();
            m = s_lcnt; if (m > LOCAL_CAP) m = LOCAL_CAP;
        }

        // radix-narrow to <= OUT_CAP keys, seeded at the first differing byte
        u64 thr;
        if (m <= OUT_CAP) {
            thr = 0ULL;
        } else {
            u64 kmn = ~0ULL, kmx = 0ULL;
            for (int i = tid; i < m; i += 512) {
                u64 k = keys[i];
                kmn = k < kmn ? k : kmn; kmx = k > kmx ? k : kmx;
            }
            for (int off = 32; off > 0; off >>= 1) {
                u64 a = __shfl_down(kmn, off), c = __shfl_down(kmx, off);
                if (lane + off < 64) { kmn = a < kmn ? a : kmn; kmx = c > kmx ? c : kmx; }
            }
            if (lane == 0) { wmin[wv] = kmn; wmax[wv] = kmx; }
            __syncthreads();
            if (tid == 0) {
                u64 mn = wmin[0], mx = wmax[0];
                for (int w2 = 1; w2 < 8; ++w2) {
                    mn = wmin[w2] < mn ? wmin[w2] : mn;
                    mx = wmax[w2] > mx ? wmax[w2] : mx;
                }
                u64 diff = mn ^ mx;
                int hb = 63 - __builtin_clzll(diff | 1ULL);
                int st = (hb >> 3) << 3;
                s_shift0 = st;
                s_prefix = (st == 56) ? 0ULL : (mx >> (st + 8));
                s_cntgt = 0u;
            }
            __syncthreads();
            int shift = s_shift0;
            for (; shift >= 0; shift -= 8) {
                if (tid < 256) h256[tid] = 0u;
                __syncthreads();
                u64 pref = s_prefix;
                unsigned int cg = s_cntgt;
                for (int i = tid; i < m; i += 512) {
                    u64 k = keys[i];
                    bool match = (shift == 56) || ((k >> (shift + 8)) == pref);
                    if (match) atomicAdd(&h256[(unsigned int)((k >> shift) & 0xFF)], 1u);
                }
                __syncthreads();
                if (wv == 0) {
                    unsigned int b4[4]; unsigned int lt = 0;
                    for (int j = 0; j < 4; ++j) { b4[j] = h256[lane * 4 + j]; lt += b4[j]; }
                    unsigned int sx = lt;
                    for (int off = 1; off < 64; off <<= 1) {
                        unsigned int t2 = __shfl_down(sx, off);
                        sx += (lane + off < 64) ? t2 : 0u;
                    }
                    unsigned int after = sx - lt;
                    unsigned int target = (unsigned)KK - cg;
                    unsigned int sn2 = after;
                    for (int j = 3; j >= 0; --j) {
                        unsigned int s = sn2 + b4[j];
                        if (s >= target && sn2 < target) {
                            unsigned int bin = (unsigned)(lane * 4 + j);
                            s_region = b4[j];
                            s_cntgt = cg + sn2;
                            s_prefix = (shift == 56) ? (u64)bin : ((pref << 8) | (u64)bin);
                        }
                        sn2 = s;
                    }
                }
                __syncthreads();
                if (s_cntgt + s_region <= (unsigned)OUT_CAP) break;
            }
            if (shift < 0) shift = 0;
            thr = s_prefix << shift;
        }

        // write keys >= thr to this slice's private global region; publish tag
        if (tid == 0) s_sc = 0;
        __syncthreads();
        u64* outslice = cand + (size_t)(b * SLICES + x) * OUT_CAP;
        for (int r0 = 0; r0 < LOCAL_CAP / 512; ++r0) {
            int i = tid + r0 * 512;
            u64 k = (i < m) ? keys[i] : 0ULL;
            bool pq = (i < m) && (k >= thr);
            u64 mb = __ballot(pq);
            int pre = __popcll(mb & ((1ULL << lane) - 1ULL));
            int tt = __popcll(mb);
            int base = 0;
            if (lane == 0 && tt > 0) base = atomicAdd(&s_sc, tt);
            base = __shfl(base, 0);
            if (pq && base + pre < OUT_CAP) outslice[base + pre] = k;
        }
        __syncthreads();          // drains vmcnt -> all cand stores complete
        if (tid == 0) {
            int c = s_sc; if (c > OUT_CAP) c = OUT_CAP;
            __threadfence();      // device-scope release of cand stores
            __hip_atomic_store(&cnts[b * SLICES + x], TAG | (unsigned int)c,
                               __ATOMIC_RELAXED, __HIP_MEMORY_SCOPE_AGENT);
        }
    }
    if (x != 0) return;

    // ======================= FINAL phase (32 blocks, x==0) =======================
    unsigned int* fhist = (unsigned int*)smem;            // [0, 16384)
    unsigned int* pfx   = ((unsigned int*)smem) + 4096;   // [16384, 32768)
    u64* tmp = (u64*)((char*)smem + 32768);               // [32768, 37888)
    float* sboxes = (float*)((char*)smem + 37888);        // [37888, 47888) stride 5
    float* sscore = (float*)((char*)smem + 47888);
    int* slabel = (int*)((char*)smem + 49888);
    int* clist  = (int*)((char*)smem + 51888);
    const u64* cb = cand + (size_t)b * SLICES * OUT_CAP;

    // spin-wait for the 8 slice tags of this batch, then acquire
    if (tid < SLICES) {
        const unsigned int* cp = cnts + b * SLICES + tid;
        unsigned int v;
        for (;;) {
            v = __hip_atomic_load(cp, __ATOMIC_RELAXED, __HIP_MEMORY_SCOPE_AGENT);
            if ((v & TAGMASK) == TAG) break;
            __builtin_amdgcn_s_sleep(1);
        }
        int c = (int)(v & 0x3FFu); if (c > OUT_CAP) c = OUT_CAP;
        scnt[tid] = c;
    }
    if (tid == 0) { s_thrbin = 0; s_fb = 0; s_nk = 0; s_stop = 0; }
    __syncthreads();
    __threadfence();              // device-scope acquire before reading cand
    if (tid == 0) {
        int acc = 0;
        for (int s = 0; s < SLICES; ++s) { soff[s] = acc; acc += scnt[s]; }
        soff[SLICES] = acc;
    }
    __syncthreads();
    const int m = soff[SLICES];
    int so1 = soff[1], so2 = soff[2], so3 = soff[3], so4 = soff[4];
    int so5 = soff[5], so6 = soff[6], so7 = soff[7];

    // ---- B: zero hist + flat one-shot key load to registers + min/max ----
    for (int i = tid; i < 4096; i += 512) fhist[i] = 0u;
    u64 kreg[FITER];
    u64 kmn = ~0ULL, kmx = 0ULL;
    #pragma unroll
    for (int r0 = 0; r0 < FITER; ++r0) {
        int i = tid + r0 * 512;
        u64 k = 0ULL;
        if (i < m) {
            int s = (i >= so1) + (i >= so2) + (i >= so3) + (i >= so4)
                  + (i >= so5) + (i >= so6) + (i >= so7);
            int base = (s == 0) ? 0 : soff[s];
            k = cb[(size_t)s * OUT_CAP + (i - base)];
            kmn = k < kmn ? k : kmn; kmx = k > kmx ? k : kmx;
        }
        kreg[r0] = k;
    }
    for (int off = 32; off > 0; off >>= 1) {
        u64 a = __shfl_down(kmn, off), c2 = __shfl_down(kmx, off);
        if (lane + off < 64) { kmn = a < kmn ? a : kmn; kmx = c2 > kmx ? c2 : kmx; }
    }
    if (lane == 0) { wmin[wv] = kmn; wmax[wv] = kmx; }
    __syncthreads();
    if (tid == 0) {
        u64 mn = wmin[0], mx = wmax[0];
        for (int w2 = 1; w2 < 8; ++w2) {
            mn = wmin[w2] < mn ? wmin[w2] : mn;
            mx = wmax[w2] > mx ? wmax[w2] : mx;
        }
        s_kmn = mn; s_kmx = mx;
        u64 diff = mn ^ mx;
        int hb = 63 - __builtin_clzll(diff | 1ULL);
        int sh = hb - 11; if (sh < 0) sh = 0;
        s_shift = sh;
    }
    __syncthreads();
    const int shift = s_shift;

    // ---- C: 12-bit histogram of the varying window (from registers) ----
    #pragma unroll
    for (int r0 = 0; r0 < FITER; ++r0) {
        int i = tid + r0 * 512;
        if (i < m) atomicAdd(&fhist[(unsigned int)((kreg[r0] >> shift) & 0xFFFu)], 1u);
    }
    __syncthreads();

    // ---- D: descending prefix (8 bins/thread) + threshold bin ----
    unsigned int h8[8]; unsigned int lt = 0, hm = 0;
    const int g0 = tid << 3;
    #pragma unroll
    for (int j = 0; j < 8; ++j) { h8[j] = fhist[g0 + j]; lt += h8[j]; hm = h8[j] > hm ? h8[j] : hm; }
    unsigned int sfx = lt;
    for (int off = 1; off < 64; off <<= 1) {
        unsigned int t2 = __shfl_down(sfx, off);
        sfx += (lane + off < 64) ? t2 : 0u;
    }
    unsigned int mh = hm;
    for (int off = 1; off < 64; off <<= 1) {
        unsigned int t2 = __shfl_down(mh, off);
        if (lane + off < 64) mh = t2 > mh ? t2 : mh;
    }
    if (lane == 0) { wsum[wv] = sfx; wmaxh[wv] = mh; }
    __syncthreads();
    unsigned int wafter = 0;
    for (int w2 = wv + 1; w2 < 8; ++w2) wafter += wsum[w2];
    unsigned int run = wafter + (sfx - lt);
    #pragma unroll
    for (int j = 7; j >= 0; --j) {
        pfx[g0 + j] = run;
        if (run < (unsigned)KK && run + h8[j] >= (unsigned)KK) s_thrbin = g0 + j;
        run += h8[j];
    }
    if (tid == 0) {
        unsigned int mmh = 0;
        for (int w2 = 0; w2 < 8; ++w2) mmh = wmaxh[w2] > mmh ? wmaxh[w2] : mmh;
        if (mmh > 64u) s_fb = 1;
    }
    __syncthreads();
    if (tid == 0) {
        int tb = s_thrbin;
        unsigned int su = pfx[tb] + fhist[tb];
        s_selupper = (int)su;
        if (su > (unsigned)TMPCAP) s_fb = 1;
    }
    if (tid < KK) {
        sscore[tid] = -1.0f; slabel[tid] = 0;
        sboxes[tid * 5 + 0] = 0.0f; sboxes[tid * 5 + 1] = 0.0f;
        sboxes[tid * 5 + 2] = 0.0f; sboxes[tid * 5 + 3] = 0.0f;
    }
    __syncthreads();

    if (!s_fb) {
        // ---- E: scatter selected keys bin-grouped (consumes pfx) ----
        const int thrbin = s_thrbin;
        #pragma unroll
        for (int r0 = 0; r0 < FITER; ++r0) {
            int i = tid + r0 * 512;
            if (i < m) {
                u64 k = kreg[r0];
                unsigned int g = (unsigned int)((k >> shift) & 0xFFFu);
                if ((int)g >= thrbin) {
                    unsigned int p = atomicAdd(&pfx[g], 1u);
                    if (p < (unsigned)TMPCAP) tmp[p] = k;
                }
            }
        }
        __syncthreads();
        // ---- F: exact within-bin rank -> final slot; decode + gather + write ----
        int nr = s_selupper; if (nr > TMPCAP) nr = TMPCAP;
        for (int ii = tid; ii < nr; ii += 512) {
            u64 k = tmp[ii];
            unsigned int g = (unsigned int)((k >> shift) & 0xFFFu);
            unsigned int c = fhist[g];
            unsigned int base = pfx[g] - c;
            unsigned int lo = (unsigned int)k, hi = (unsigned int)(k >> 32);
            int idx = (int)(~lo);
            unsigned int bits = (hi & 0x80000000u) ? (hi & 0x7FFFFFFFu) : ~hi;
            float msc = __uint_as_float(bits);
            const float4 bx = *(const float4*)(pboxes + (((size_t)b * NN + (size_t)idx) << 2));
            int lab = plabels[(size_t)b * NN + idx];
            int rank = 0;
            for (unsigned int q = 0; q < c; ++q) {
                u64 o = tmp[base + q];
                rank += (o > k) ? 1 : 0;
            }
            int fin = (int)base + rank;
            if (fin < KK) {
                sboxes[fin * 5 + 0] = bx.x; sboxes[fin * 5 + 1] = bx.y;
                sboxes[fin * 5 + 2] = bx.z; sboxes[fin * 5 + 3] = bx.w;
                sscore[fin] = msc; slabel[fin] = lab;
            }
        }
        __syncthreads();
    } else {
        // ---- exact fallback: seeded byte-radix + ballot gather + readlane rank ----
        if (tid == 0) {
            u64 mn = s_kmn, mx = s_kmx;
            u64 diff = mn ^ mx;
            int hb = 63 - __builtin_clzll(diff | 1ULL);
            int st = (hb >> 3) << 3;
            s_bsh = st;
            s_prefix = (st == 56) ? 0ULL : (mx >> (st + 8));
            s_cntgt = 0u;
        }
        __syncthreads();
        int sh2 = s_bsh;
        for (; sh2 >= 0; sh2 -= 8) {
            if (tid < 256) fhist[tid] = 0u;
            __syncthreads();
            u64 pref = s_prefix;
            unsigned int cg = s_cntgt;
            #pragma unroll
            for (int r0 = 0; r0 < FITER; ++r0) {
                int i = tid + r0 * 512;
                if (i < m) {
                    u64 k = kreg[r0];
                    bool match = (sh2 == 56) || ((k >> (sh2 + 8)) == pref);
                    if (match) atomicAdd(&fhist[(unsigned int)((k >> sh2) & 0xFF)], 1u);
                }
            }
            __syncthreads();
            if (wv == 0) {
                unsigned int b4[4]; unsigned int lt2 = 0;
                for (int j = 0; j < 4; ++j) { b4[j] = fhist[lane * 4 + j]; lt2 += b4[j]; }
                unsigned int sx = lt2;
                for (int off = 1; off < 64; off <<= 1) {
                    unsigned int t2 = __shfl_down(sx, off);
                    sx += (lane + off < 64) ? t2 : 0u;
                }
                unsigned int after = sx - lt2;
                unsigned int target = (unsigned)KK - cg;
                unsigned int sn2 = after;
                for (int j = 3; j >= 0; --j) {
                    unsigned int s = sn2 + b4[j];
                    if (s >= target && sn2 < target) {
                        unsigned int bin = (unsigned)(lane * 4 + j);
                        s_region = b4[j];
                        s_cntgt = cg + sn2;
                        s_prefix = (sh2 == 56) ? (u64)bin : ((pref << 8) | (u64)bin);
                    }
                    sn2 = s;
                }
            }
            __syncthreads();
            if (s_cntgt + s_region <= (unsigned)OUT_CAP) break;
        }
        if (sh2 < 0) sh2 = 0;
        u64 thr2 = s_prefix << sh2;
        int seln = (int)(s_cntgt + s_region);
        if (seln > TMPCAP) seln = TMPCAP;
        if (tid == 0) s_sc = 0;
        __syncthreads();
        #pragma unroll
        for (int r0 = 0; r0 < FITER; ++r0) {
            int i = tid + r0 * 512;
            u64 k = (i < m) ? kreg[r0] : 0ULL;
            bool pq = (i < m) && (k >= thr2);
            u64 mb = __ballot(pq);
            int pre = __popcll(mb & ((1ULL << lane) - 1ULL));
            int tt = __popcll(mb);
            int bse = 0;
            if (lane == 0 && tt > 0) bse = atomicAdd(&s_sc, tt);
            bse = __shfl(bse, 0);
            if (pq) { int pos = bse + pre; if (pos < TMPCAP) tmp[pos] = k; }
        }
        __syncthreads();
        for (int r0 = 0; r0 < 2; ++r0) {
            int ii = tid + r0 * 512;
            if (ii - lane < seln) {                  // wave-uniform guard
                u64 myk = (ii < seln) ? tmp[ii] : 0ULL;
                int r = 0;
                for (int base = 0; base < seln; base += 64) {
                    int i2 = base + lane;
                    u64 other = (i2 < seln) ? tmp[i2] : 0ULL;
                    unsigned int olo = (unsigned int)other, ohi = (unsigned int)(other >> 32);
                    int lim = seln - base; if (lim > 64) lim = 64;
                    for (int t2 = 0; t2 < lim; ++t2) {
                        unsigned int blo = (unsigned int)__builtin_amdgcn_readlane((int)olo, t2);
                        unsigned int bhi = (unsigned int)__builtin_amdgcn_readlane((int)ohi, t2);
                        u64 o = ((u64)bhi << 32) | (u64)blo;
                        r += (o > myk) ? 1 : 0;
                    }
                }
                if (ii < seln && r < KK) {
                    unsigned int lo = (unsigned int)myk, hi = (unsigned int)(myk >> 32);
                    int idx = (int)(~lo);
                    unsigned int bits = (hi & 0x80000000u) ? (hi & 0x7FFFFFFFu) : ~hi;
                    float msc = __uint_as_float(bits);
                    const float4 bx = *(const float4*)(pboxes + (((size_t)b * NN + (size_t)idx) << 2));
                    int lab = plabels[(size_t)b * NN + idx];
                    sboxes[r * 5 + 0] = bx.x; sboxes[r * 5 + 1] = bx.y;
                    sboxes[r * 5 + 2] = bx.z; sboxes[r * 5 + 3] = bx.w;
                    sscore[r] = msc; slabel[r] = lab;
                }
            }
        }
        __syncthreads();
    }

    // ---- G: valid/maxc, class partition, IoU masks, chunked NMS, outputs ----
    float sc = (tid < KK) ? sscore[tid] : -1.0f;
    bool vq = (tid < KK) && (sc > CONF);
    u64 bm = __ballot(vq);
    if (lane == 0) validw[wv] = bm;
    float lm = vq ? fmaxf(fmaxf(sboxes[tid * 5 + 0], sboxes[tid * 5 + 1]),
                          fmaxf(sboxes[tid * 5 + 2], sboxes[tid * 5 + 3])) : 0.0f;
    for (int off = 32; off > 0; off >>= 1) lm = fmaxf(lm, __shfl_down(lm, off));
    if (lane == 0) wred[wv] = lm;
    __syncthreads();
    if (tid < 64) {
        float xx = (tid < 8) ? wred[tid] : 0.0f;
        for (int off = 4; off > 0; off >>= 1) xx = fmaxf(xx, __shfl_down(xx, off));
        if (tid == 0) s_maxc = xx;
    }
    if (tid < 21) { ccnt[tid] = 0; cfill[tid] = 0; }
    if (tid < 8) sremv[tid] = 0ULL;
    __syncthreads();
    if (tid < KK) atomicAdd(&ccnt[slabel[tid]], 1);
    __syncthreads();
    if (tid == 0) {
        int acc = 0;
        for (int c = 0; c < 21; ++c) { coff[c] = acc; acc += ccnt[c]; }
        coff[21] = acc;
    }
    __syncthreads();
    if (tid < KK) {
        int c = slabel[tid];
        int pos = atomicAdd(&cfill[c], 1);
        clist[coff[c] + pos] = tid;
    }
    // overlay transposed masks msk[word][box] on smem[0..32768) (fhist/pfx dead)
    u64 (*msk)[512] = (u64(*)[512])smem;
    for (int i = tid; i < 8 * 512; i += 512) ((u64*)smem)[i] = 0ULL;
    __syncthreads();

    float ap1 = s_maxc + 1.0f;
    if (tid < KK) {
        int c = slabel[tid];
        int n = ccnt[c], base0 = coff[c];
        float aoff = (float)c * ap1;
        float a0 = sboxes[tid * 5 + 0] + aoff, a1 = sboxes[tid * 5 + 1] + aoff;
        float a2 = sboxes[tid * 5 + 2] + aoff, a3 = sboxes[tid * 5 + 3] + aoff;
        float areaA = (a2 - a0) * (a3 - a1);
        for (int q = 0; q < n; ++q) {
            int j = clist[base0 + q];
            float b0 = sboxes[j * 5 + 0] + aoff, b1f = sboxes[j * 5 + 1] + aoff;
            float b2f = sboxes[j * 5 + 2] + aoff, b3f = sboxes[j * 5 + 3] + aoff;
            float lt0 = fmaxf(a0, b0), lt1 = fmaxf(a1, b1f);
            float rb0 = fminf(a2, b2f), rb1 = fminf(a3, b3f);
            float ww = fmaxf(rb0 - lt0, 0.0f), hh = fmaxf(rb1 - lt1, 0.0f);
            float inter = ww * hh;
            float areaB = (b2f - b0) * (b3f - b1f);
            float iou = inter / (areaA + areaB - inter);
            if (iou > NMSTHR) msk[j >> 6][tid] |= (1ULL << (j & 63));
        }
    }
    __syncthreads();

    // chunked greedy NMS: intra-chunk serial pass in registers (readlane),
    // cross-chunk suppression OR'd in parallel by waves c+1..7.
    for (int c = 0; c < 8; ++c) {
        if (wv == 0) {
            u64 rowc = msk[c][c * 64 + lane];
            unsigned int rl = (unsigned int)rowc, rh = (unsigned int)(rowc >> 32);
            u64 cur = sremv[c];
            u64 vv = validw[c];
            u64 km = 0ULL;
            int nk = s_nk;
            for (int j = 0; j < 64; ++j) {
                if (nk >= KEEPN) break;
                bool alive = (((vv >> j) & 1ULL) != 0ULL) && (((cur >> j) & 1ULL) == 0ULL);
                if (alive) {
                    if (lane == 0) kept[nk] = c * 64 + j;
                    u64 rv = ((u64)(unsigned int)__builtin_amdgcn_readlane((int)rh, j) << 32)
                           |  (u64)(unsigned int)__builtin_amdgcn_readlane((int)rl, j);
                    cur |= rv;
                    km |= (1ULL << j);
                    ++nk;
                }
            }
            if (lane == 0) { s_km = km; s_nk = nk; sremv[c] = cur; s_stop = (nk >= KEEPN) ? 1 : 0; }
        }
        __syncthreads();
        if (s_stop || c == 7) break;
        if (wv > c) {
            u64 km = s_km;
            u64 v = ((km >> lane) & 1ULL) ? msk[wv][c * 64 + lane] : 0ULL;
            for (int off2 = 32; off2 > 0; off2 >>= 1) v |= __shfl_xor(v, off2);
            if (lane == 0) sremv[wv] |= v;
        }
        __syncthreads();
    }

    if (tid < KEEPN) {
        const int O_BOX = BB * KEEPN;
        const int O_LAB = BB * KEEPN * 5;
        const int O_SCO = BB * KEEPN * 6;
        const int O_VAL = BB * KEEPN * 7;
        bool q = tid < s_nk;
        int i = q ? kept[tid] : 0;
        int g = b * KEEPN + tid;
        out[g]                 = q ? (float)b : -1.0f;
        out[O_BOX + g * 4 + 0] = q ? sboxes[i * 5 + 0] : 0.0f;
        out[O_BOX + g * 4 + 1] = q ? sboxes[i * 5 + 1] : 0.0f;
        out[O_BOX + g * 4 + 2] = q ? sboxes[i * 5 + 2] : 0.0f;
        out[O_BOX + g * 4 + 3] = q ? sboxes[i * 5 + 3] : 0.0f;
        out[O_LAB + g]         = q ? (float)slabel[i] : -1.0f;
        out[O_SCO + g]         = q ? sscore[i] : 0.0f;
        out[O_VAL + g]         = q ? 1.0f : 0.0f;
    }

    // clear this batch's tags so the next call (or rocprof replay) must wait
    // for fresh select writes; kernel-boundary ordering makes this visible.
    if (tid < SLICES) cnts[b * SLICES + tid] = 0u;
}

extern "C" void kernel_launch(void* const* d_in, const int* in_sizes, int n_in,
                              void* d_out, int out_size, void* d_ws, size_t ws_size,
                              hipStream_t stream) {
    const float* pscores = (const float*)d_in[0];
    const float* pboxes  = (const float*)d_in[1];
    const int*   plabels = (const int*)d_in[2];
    float* out = (float*)d_out;

    uint8_t* ws = (uint8_t*)d_ws;
    u64*          cand = (u64*)(ws + 0);
    unsigned int* cnts = (unsigned int*)(ws + 1179648);

    fused_kernel<<<dim3(SLICES, BB), 512, 0, stream>>>((const float4*)pscores, pboxes,
                                                       plabels, cand, cnts, out);
}

// Round 7
// 196.905 us; speedup vs baseline: 1.1963x; 1.1963x over previous
//
#include <hip/hip_runtime.h>
#include <stdint.h>

#pragma clang fp contract(off)

#define BB 32
#define NN 200000
#define N4 50000
#define KK 500
#define KEEPN 100
#define CONF 0.05f
#define NMSTHR 0.5f
#define SLICES 8
#define SLICE_F4 6250          // float4 per slice (25000 elems)
#define LBINS 8192
#define LSHIFT 19              // top 13 bits of ordkey
#define LOCAL_CAP 2048
#define OUT_CAP 576
#define TMPCAP 640
#define OK0 0xBF733333u        // ordkey(0.95f) — fast-path candidate gate

typedef unsigned long long u64;

// ---- workspace layout (bytes) ----
// 0       : cand 32*8*576*8 = 1179648   (slices fully rewritten each call)
// 1179648 : cnts 256*4 = 1024           (fully rewritten each call; no memset)

__device__ __forceinline__ unsigned int ordkey(float s) {
    unsigned int u = __float_as_uint(s);
    return (u & 0x80000000u) ? ~u : (u | 0x80000000u);
}

// wave-aggregated LDS append: one shared-counter atomic per wave, ordered scatter
__device__ __forceinline__ void wappend(bool pred, u64 key, u64* keys, int* lcnt, int lane) {
    u64 bm = __ballot(pred);
    int pre = __popcll(bm & ((1ULL << lane) - 1ULL));
    int tt  = __popcll(bm);
    int base = 0;
    if (lane == 0 && tt > 0) base = atomicAdd(lcnt, tt);
    base = __shfl(base, 0);
    if (pred) { int pos = base + pre; if (pos < LOCAL_CAP) keys[pos] = key; }
}

// ---- stage 1: per-slice top-500 superset via direct gate (no histogram) ----
// Fast path: single pass, append ordkey>=OK0 (~1250/slice expected).
// Fallback (count<KK or >LOCAL_CAP): exact two-pass 13-bit histogram.
__global__ __launch_bounds__(1024) void select_kernel(const float4* __restrict__ ps4,
                                                      u64* __restrict__ cand,
                                                      unsigned int* __restrict__ cnts) {
    __shared__ unsigned int hist[LBINS];     // 32 KB (fallback only)
    __shared__ u64 keys[LOCAL_CAP];          // 16 KB
    __shared__ unsigned int h[256];
    __shared__ unsigned int wsum[16];
    __shared__ u64 wmin[16], wmax[16];
    __shared__ u64 s_prefix;
    __shared__ unsigned int s_t13, s_region, s_cntgt;
    __shared__ int s_lcnt, s_sc, s_shift0;

    const int b = blockIdx.y, x = blockIdx.x;
    const int tid = threadIdx.x, lane = tid & 63, wv = tid >> 6;
    const float4* p = ps4 + (size_t)b * N4 + (size_t)x * SLICE_F4;
    const int ebase = x * (SLICE_F4 * 4);

    if (tid == 0) s_lcnt = 0;
    __syncthreads();

    // pass A (fast): gate + wave-aggregated compact, single read of the slice
    for (int i = tid; i < SLICE_F4; i += 1024) {
        float4 v = p[i];
        int n = ebase + (i << 2);
        unsigned int ux = ordkey(v.x), uy = ordkey(v.y);
        unsigned int uz = ordkey(v.z), uw = ordkey(v.w);
        wappend(ux >= OK0, ((u64)ux << 32) | (unsigned int)(~(unsigned int)(n)),     keys, &s_lcnt, lane);
        wappend(uy >= OK0, ((u64)uy << 32) | (unsigned int)(~(unsigned int)(n + 1)), keys, &s_lcnt, lane);
        wappend(uz >= OK0, ((u64)uz << 32) | (unsigned int)(~(unsigned int)(n + 2)), keys, &s_lcnt, lane);
        wappend(uw >= OK0, ((u64)uw << 32) | (unsigned int)(~(unsigned int)(n + 3)), keys, &s_lcnt, lane);
    }
    __syncthreads();
    int m = s_lcnt;

    if (m < KK || m > LOCAL_CAP) {
        // ---- exact fallback: two-pass 13-bit histogram path ----
        for (int i = tid; i < LBINS; i += 1024) hist[i] = 0;
        __syncthreads();
        for (int i = tid; i < SLICE_F4; i += 1024) {
            float4 v = p[i];
            atomicAdd(&hist[ordkey(v.x) >> LSHIFT], 1u);
            atomicAdd(&hist[ordkey(v.y) >> LSHIFT], 1u);
            atomicAdd(&hist[ordkey(v.z) >> LSHIFT], 1u);
            atomicAdd(&hist[ordkey(v.w) >> LSHIFT], 1u);
        }
        __syncthreads();
        unsigned int v8[8], tot = 0;
        for (int j = 0; j < 8; ++j) { v8[j] = hist[tid * 8 + j]; tot += v8[j]; }
        unsigned int sfx = tot;
        for (int off = 1; off < 64; off <<= 1) {
            unsigned int t2 = __shfl_down(sfx, off);
            sfx += (lane + off < 64) ? t2 : 0u;
        }
        if (lane == 0) wsum[wv] = sfx;
        __syncthreads();
        unsigned int wafter = 0;
        for (int w2 = wv + 1; w2 < 16; ++w2) wafter += wsum[w2];
        unsigned int sn = wafter + (sfx - tot);
        for (int j = 7; j >= 0; --j) {
            unsigned int s = sn + v8[j];
            if (s >= (unsigned)KK && sn < (unsigned)KK) s_t13 = (unsigned)(tid * 8 + j);
            sn = s;
        }
        if (tid == 0) s_lcnt = 0;
        __syncthreads();
        const unsigned int t13 = s_t13;
        for (int i = tid; i < SLICE_F4; i += 1024) {
            float4 v = p[i];
            int n = ebase + (i << 2);
            unsigned int u;
            u = ordkey(v.x); if ((u >> LSHIFT) >= t13) { int pos = atomicAdd(&s_lcnt, 1);
                if (pos < LOCAL_CAP) keys[pos] = ((u64)u << 32) | (unsigned int)(~(unsigned int)(n)); }
            u = ordkey(v.y); if ((u >> LSHIFT) >= t13) { int pos = atomicAdd(&s_lcnt, 1);
                if (pos < LOCAL_CAP) keys[pos] = ((u64)u << 32) | (unsigned int)(~(unsigned int)(n + 1)); }
            u = ordkey(v.z); if ((u >> LSHIFT) >= t13) { int pos = atomicAdd(&s_lcnt, 1);
                if (pos < LOCAL_CAP) keys[pos] = ((u64)u << 32) | (unsigned int)(~(unsigned int)(n + 2)); }
            u = ordkey(v.w); if ((u >> LSHIFT) >= t13) { int pos = atomicAdd(&s_lcnt, 1);
                if (pos < LOCAL_CAP) keys[pos] = ((u64)u << 32) | (unsigned int)(~(unsigned int)(n + 3)); }
        }
        __syncthreads();
        m = s_lcnt; if (m > LOCAL_CAP) m = LOCAL_CAP;
    }

    // radix-narrow to <= OUT_CAP keys, seeded at the first differing byte
    u64 thr; int seln;
    if (m <= OUT_CAP) {
        thr = 0ULL; seln = m;
    } else {
        // min/max prescan -> skip common-prefix (same-bin storm) passes
        u64 kmn = ~0ULL, kmx = 0ULL;
        for (int i = tid; i < m; i += 1024) {
            u64 k = keys[i];
            kmn = k < kmn ? k : kmn; kmx = k > kmx ? k : kmx;
        }
        for (int off = 32; off > 0; off >>= 1) {
            u64 a = __shfl_down(kmn, off), c = __shfl_down(kmx, off);
            if (lane + off < 64) { kmn = a < kmn ? a : kmn; kmx = c > kmx ? c : kmx; }
        }
        if (lane == 0) { wmin[wv] = kmn; wmax[wv] = kmx; }
        __syncthreads();
        if (tid == 0) {
            u64 mn = wmin[0], mx = wmax[0];
            for (int w2 = 1; w2 < 16; ++w2) {
                mn = wmin[w2] < mn ? wmin[w2] : mn;
                mx = wmax[w2] > mx ? wmax[w2] : mx;
            }
            u64 diff = mn ^ mx;
            int hb = 63 - __builtin_clzll(diff | 1ULL);
            int st = (hb >> 3) << 3;
            s_shift0 = st;
            s_prefix = (st == 56) ? 0ULL : (mx >> (st + 8));
            s_cntgt = 0u;
        }
        __syncthreads();
        int shift = s_shift0;
        for (; shift >= 0; shift -= 8) {
            if (tid < 256) h[tid] = 0u;
            __syncthreads();
            u64 pref = s_prefix;
            unsigned int cg = s_cntgt;
            for (int i = tid; i < m; i += 1024) {
                u64 k = keys[i];
                bool match = (shift == 56) || ((k >> (shift + 8)) == pref);
                if (match) atomicAdd(&h[(unsigned int)((k >> shift) & 0xFF)], 1u);
            }
            __syncthreads();
            if (wv == 0) {
                unsigned int b4[4]; unsigned int lt = 0;
                for (int j = 0; j < 4; ++j) { b4[j] = h[lane * 4 + j]; lt += b4[j]; }
                unsigned int sx = lt;
                for (int off = 1; off < 64; off <<= 1) {
                    unsigned int t2 = __shfl_down(sx, off);
                    sx += (lane + off < 64) ? t2 : 0u;
                }
                unsigned int after = sx - lt;
                unsigned int target = (unsigned)KK - cg;
                unsigned int sn2 = after;
                for (int j = 3; j >= 0; --j) {
                    unsigned int s = sn2 + b4[j];
                    if (s >= target && sn2 < target) {
                        unsigned int bin = (unsigned)(lane * 4 + j);
                        s_region = b4[j];
                        s_cntgt = cg + sn2;
                        s_prefix = (shift == 56) ? (u64)bin : ((pref << 8) | (u64)bin);
                    }
                    sn2 = s;
                }
            }
            __syncthreads();
            if (s_cntgt + s_region <= (unsigned)OUT_CAP) break;
        }
        if (shift < 0) shift = 0;
        thr = s_prefix << shift;
        seln = (int)(s_cntgt + s_region);
    }
    (void)seln;

    // write keys >= thr to this slice's private global region
    if (tid == 0) s_sc = 0;
    __syncthreads();
    u64* outslice = cand + (size_t)(b * SLICES + x) * OUT_CAP;
    for (int r0 = 0; r0 < LOCAL_CAP / 1024; ++r0) {
        int i = tid + r0 * 1024;
        u64 k = (i < m) ? keys[i] : 0ULL;
        bool pq = (i < m) && (k >= thr);
        u64 mb = __ballot(pq);
        int pre = __popcll(mb & ((1ULL << lane) - 1ULL));
        int tt = __popcll(mb);
        int base = 0;
        if (lane == 0 && tt > 0) base = atomicAdd(&s_sc, tt);
        base = __shfl(base, 0);
        if (pq && base + pre < OUT_CAP) outslice[base + pre] = k;
    }
    __syncthreads();
    if (tid == 0) {
        int c = s_sc; if (c > OUT_CAP) c = OUT_CAP;
        cnts[b * SLICES + x] = (unsigned)c;
    }
}

// ---- stage 2 (512 threads, 8 waves): merge slices + exact top-500 via
//      one-pass counting sort over register-resident keys, class-partitioned
//      IoU masks, chunked greedy NMS, outputs ----
// Keys are read from global ONCE into registers (<=9/thread, flat index over
// all slices), then min/max, histogram, and scatter run from registers.
#define FITER 9                 // ceil(4608 / 512)
__global__ __launch_bounds__(512) void final_kernel(const float* __restrict__ pboxes,
                                                    const int* __restrict__ plabels,
                                                    const u64* __restrict__ cand,
                                                    const unsigned int* __restrict__ cnts,
                                                    float* __restrict__ out) {
    __shared__ u64 pool[4736];          // 37888 B multi-phase buffer
    __shared__ float sboxes[KK * 5];    // stride 5: conflict-free per-thread access
    __shared__ float sscore[KK];
    __shared__ int slabel[KK];
    __shared__ int clist[KK];
    __shared__ int scnt[SLICES];
    __shared__ int soff[SLICES + 1];
    __shared__ u64 wmin[8], wmax[8];
    __shared__ unsigned int wsum[8], wmaxh[8];
    __shared__ float wred[8];
    __shared__ int ccnt[21], coff[22], cfill[21];
    __shared__ u64 validw[8], sremv[8], s_km;
    __shared__ int kept[KEEPN];
    __shared__ u64 s_kmn, s_kmx, s_prefix;
    __shared__ unsigned int s_region, s_cntgt;
    __shared__ int s_shift, s_thrbin, s_selupper, s_fb, s_bsh, s_sc, s_nk, s_stop;
    __shared__ float s_maxc;

    unsigned int* hist = (unsigned int*)pool;          // [0, 16384)
    unsigned int* pfx  = ((unsigned int*)pool) + 4096; // [16384, 32768)
    u64* tmp = (u64*)((char*)pool + 32768);            // [32768, 37888): 640 u64

    const int b = blockIdx.x;
    const int tid = threadIdx.x;
    const int lane = tid & 63;
    const int wv = tid >> 6;                           // 0..7
    const u64* cb = cand + (size_t)b * SLICES * OUT_CAP;

    if (tid < SLICES) {
        int c = (int)cnts[b * SLICES + tid];
        scnt[tid] = c > OUT_CAP ? OUT_CAP : c;
    }
    if (tid == 0) { s_thrbin = 0; s_fb = 0; s_nk = 0; s_stop = 0; }
    __syncthreads();
    if (tid == 0) {
        int acc = 0;
        for (int s = 0; s < SLICES; ++s) { soff[s] = acc; acc += scnt[s]; }
        soff[SLICES] = acc;
    }
    __syncthreads();
    const int m = soff[SLICES];
    // slice offsets to registers (broadcast reads)
    int so1 = soff[1], so2 = soff[2], so3 = soff[3], so4 = soff[4];
    int so5 = soff[5], so6 = soff[6], so7 = soff[7];

    // ---- B: zero hist + flat one-shot key load to registers + min/max ----
    for (int i = tid; i < 4096; i += 512) hist[i] = 0u;
    u64 kreg[FITER];
    u64 kmn = ~0ULL, kmx = 0ULL;
    #pragma unroll
    for (int r0 = 0; r0 < FITER; ++r0) {
        int i = tid + r0 * 512;
        u64 k = 0ULL;
        if (i < m) {
            int s = (i >= so1) + (i >= so2) + (i >= so3) + (i >= so4)
                  + (i >= so5) + (i >= so6) + (i >= so7);
            int base = (s == 0) ? 0 : soff[s];
            k = cb[(size_t)s * OUT_CAP + (i - base)];
            kmn = k < kmn ? k : kmn; kmx = k > kmx ? k : kmx;
        }
        kreg[r0] = k;
    }
    for (int off = 32; off > 0; off >>= 1) {
        u64 a = __shfl_down(kmn, off), c2 = __shfl_down(kmx, off);
        if (lane + off < 64) { kmn = a < kmn ? a : kmn; kmx = c2 > kmx ? c2 : kmx; }
    }
    if (lane == 0) { wmin[wv] = kmn; wmax[wv] = kmx; }
    __syncthreads();
    if (tid == 0) {
        u64 mn = wmin[0], mx = wmax[0];
        for (int w2 = 1; w2 < 8; ++w2) {
            mn = wmin[w2] < mn ? wmin[w2] : mn;
            mx = wmax[w2] > mx ? wmax[w2] : mx;
        }
        s_kmn = mn; s_kmx = mx;
        u64 diff = mn ^ mx;
        int hb = 63 - __builtin_clzll(diff | 1ULL);
        int sh = hb - 11; if (sh < 0) sh = 0;
        s_shift = sh;                       // window [sh, sh+12): top varying bits
    }
    __syncthreads();
    const int shift = s_shift;

    // ---- C: 12-bit histogram of the varying window (from registers) ----
    #pragma unroll
    for (int r0 = 0; r0 < FITER; ++r0) {
        int i = tid + r0 * 512;
        if (i < m) atomicAdd(&hist[(unsigned int)((kreg[r0] >> shift) & 0xFFFu)], 1u);
    }
    __syncthreads();

    // ---- D: descending prefix (8 bins/thread) + threshold bin ----
    unsigned int h8[8]; unsigned int lt = 0, hm = 0;
    const int g0 = tid << 3;
    #pragma unroll
    for (int j = 0; j < 8; ++j) { h8[j] = hist[g0 + j]; lt += h8[j]; hm = h8[j] > hm ? h8[j] : hm; }
    unsigned int sfx = lt;
    for (int off = 1; off < 64; off <<= 1) {
        unsigned int t2 = __shfl_down(sfx, off);
        sfx += (lane + off < 64) ? t2 : 0u;
    }
    unsigned int mh = hm;
    for (int off = 1; off < 64; off <<= 1) {
        unsigned int t2 = __shfl_down(mh, off);
        if (lane + off < 64) mh = t2 > mh ? t2 : mh;
    }
    if (lane == 0) { wsum[wv] = sfx; wmaxh[wv] = mh; }
    __syncthreads();
    unsigned int wafter = 0;
    for (int w2 = wv + 1; w2 < 8; ++w2) wafter += wsum[w2];
    unsigned int run = wafter + (sfx - lt);
    #pragma unroll
    for (int j = 7; j >= 0; --j) {
        pfx[g0 + j] = run;
        if (run < (unsigned)KK && run + h8[j] >= (unsigned)KK) s_thrbin = g0 + j;
        run += h8[j];
    }
    if (tid == 0) {
        unsigned int mmh = 0;
        for (int w2 = 0; w2 < 8; ++w2) mmh = wmaxh[w2] > mmh ? wmaxh[w2] : mmh;
        if (mmh > 64u) s_fb = 1;            // within-bin rank bound
    }
    __syncthreads();
    if (tid == 0) {
        int tb = s_thrbin;
        unsigned int su = pfx[tb] + hist[tb];   // count selected (bins >= thrbin)
        s_selupper = (int)su;
        if (su > (unsigned)TMPCAP) s_fb = 1;
    }
    if (tid < KK) {
        sscore[tid] = -1.0f; slabel[tid] = 0;
        sboxes[tid * 5 + 0] = 0.0f; sboxes[tid * 5 + 1] = 0.0f;
        sboxes[tid * 5 + 2] = 0.0f; sboxes[tid * 5 + 3] = 0.0f;
    }
    __syncthreads();

    if (!s_fb) {
        // ---- E: scatter selected keys bin-grouped (consumes pfx) ----
        const int thrbin = s_thrbin;
        #pragma unroll
        for (int r0 = 0; r0 < FITER; ++r0) {
            int i = tid + r0 * 512;
            if (i < m) {
                u64 k = kreg[r0];
                unsigned int g = (unsigned int)((k >> shift) & 0xFFFu);
                if ((int)g >= thrbin) {
                    unsigned int p = atomicAdd(&pfx[g], 1u);
                    if (p < (unsigned)TMPCAP) tmp[p] = k;
                }
            }
        }
        __syncthreads();
        // ---- F: exact within-bin rank -> final slot; decode + gather + write ----
        int nr = s_selupper; if (nr > TMPCAP) nr = TMPCAP;
        for (int ii = tid; ii < nr; ii += 512) {
            u64 k = tmp[ii];
            unsigned int g = (unsigned int)((k >> shift) & 0xFFFu);
            unsigned int c = hist[g];
            unsigned int base = pfx[g] - c;         // pfx now = orig + c
            // decode + issue scattered loads before the rank loop (latency overlap)
            unsigned int lo = (unsigned int)k, hi = (unsigned int)(k >> 32);
            int idx = (int)(~lo);
            unsigned int bits = (hi & 0x80000000u) ? (hi & 0x7FFFFFFFu) : ~hi;
            float msc = __uint_as_float(bits);
            const float4 bx = *(const float4*)(pboxes + (((size_t)b * NN + (size_t)idx) << 2));
            int lab = plabels[(size_t)b * NN + idx];
            int rank = 0;
            for (unsigned int q = 0; q < c; ++q) {
                u64 o = tmp[base + q];
                rank += (o > k) ? 1 : 0;
            }
            int fin = (int)base + rank;             // exact global descending rank
            if (fin < KK) {
                sboxes[fin * 5 + 0] = bx.x; sboxes[fin * 5 + 1] = bx.y;
                sboxes[fin * 5 + 2] = bx.z; sboxes[fin * 5 + 3] = bx.w;
                sscore[fin] = msc; slabel[fin] = lab;
            }
        }
        __syncthreads();
    } else {
        // ---- exact fallback: seeded byte-radix + ballot gather + readlane rank ----
        if (tid == 0) {
            u64 mn = s_kmn, mx = s_kmx;
            u64 diff = mn ^ mx;
            int hb = 63 - __builtin_clzll(diff | 1ULL);
            int st = (hb >> 3) << 3;
            s_bsh = st;
            s_prefix = (st == 56) ? 0ULL : (mx >> (st + 8));
            s_cntgt = 0u;
        }
        __syncthreads();
        int sh2 = s_bsh;
        for (; sh2 >= 0; sh2 -= 8) {
            if (tid < 256) hist[tid] = 0u;
            __syncthreads();
            u64 pref = s_prefix;
            unsigned int cg = s_cntgt;
            #pragma unroll
            for (int r0 = 0; r0 < FITER; ++r0) {
                int i = tid + r0 * 512;
                if (i < m) {
                    u64 k = kreg[r0];
                    bool match = (sh2 == 56) || ((k >> (sh2 + 8)) == pref);
                    if (match) atomicAdd(&hist[(unsigned int)((k >> sh2) & 0xFF)], 1u);
                }
            }
            __syncthreads();
            if (wv == 0) {
                unsigned int b4[4]; unsigned int lt2 = 0;
                for (int j = 0; j < 4; ++j) { b4[j] = hist[lane * 4 + j]; lt2 += b4[j]; }
                unsigned int sx = lt2;
                for (int off = 1; off < 64; off <<= 1) {
                    unsigned int t2 = __shfl_down(sx, off);
                    sx += (lane + off < 64) ? t2 : 0u;
                }
                unsigned int after = sx - lt2;
                unsigned int target = (unsigned)KK - cg;
                unsigned int sn2 = after;
                for (int j = 3; j >= 0; --j) {
                    unsigned int s = sn2 + b4[j];
                    if (s >= target && sn2 < target) {
                        unsigned int bin = (unsigned)(lane * 4 + j);
                        s_region = b4[j];
                        s_cntgt = cg + sn2;
                        s_prefix = (sh2 == 56) ? (u64)bin : ((pref << 8) | (u64)bin);
                    }
                    sn2 = s;
                }
            }
            __syncthreads();
            if (s_cntgt + s_region <= (unsigned)OUT_CAP) break;
        }
        if (sh2 < 0) sh2 = 0;
        u64 thr2 = s_prefix << sh2;
        int seln = (int)(s_cntgt + s_region);
        if (seln > TMPCAP) seln = TMPCAP;
        if (tid == 0) s_sc = 0;
        __syncthreads();
        #pragma unroll
        for (int r0 = 0; r0 < FITER; ++r0) {
            int i = tid + r0 * 512;
            u64 k = (i < m) ? kreg[r0] : 0ULL;
            bool pq = (i < m) && (k >= thr2);
            u64 mb = __ballot(pq);
            int pre = __popcll(mb & ((1ULL << lane) - 1ULL));
            int tt = __popcll(mb);
            int bse = 0;
            if (lane == 0 && tt > 0) bse = atomicAdd(&s_sc, tt);
            bse = __shfl(bse, 0);
            if (pq) { int pos = bse + pre; if (pos < TMPCAP) tmp[pos] = k; }
        }
        __syncthreads();
        for (int r0 = 0; r0 < 2; ++r0) {
            int ii = tid + r0 * 512;
            if (ii - lane < seln) {                  // wave-uniform guard
                u64 myk = (ii < seln) ? tmp[ii] : 0ULL;
                int r = 0;
                for (int base = 0; base < seln; base += 64) {
                    int i2 = base + lane;
                    u64 other = (i2 < seln) ? tmp[i2] : 0ULL;
                    unsigned int olo = (unsigned int)other, ohi = (unsigned int)(other >> 32);
                    int lim = seln - base; if (lim > 64) lim = 64;
                    for (int t2 = 0; t2 < lim; ++t2) {
                        unsigned int blo = (unsigned int)__builtin_amdgcn_readlane((int)olo, t2);
                        unsigned int bhi = (unsigned int)__builtin_amdgcn_readlane((int)ohi, t2);
                        u64 o = ((u64)bhi << 32) | (u64)blo;
                        r += (o > myk) ? 1 : 0;
                    }
                }
                if (ii < seln && r < KK) {
                    unsigned int lo = (unsigned int)myk, hi = (unsigned int)(myk >> 32);
                    int idx = (int)(~lo);
                    unsigned int bits = (hi & 0x80000000u) ? (hi & 0x7FFFFFFFu) : ~hi;
                    float msc = __uint_as_float(bits);
                    const float4 bx = *(const float4*)(pboxes + (((size_t)b * NN + (size_t)idx) << 2));
                    int lab = plabels[(size_t)b * NN + idx];
                    sboxes[r * 5 + 0] = bx.x; sboxes[r * 5 + 1] = bx.y;
                    sboxes[r * 5 + 2] = bx.z; sboxes[r * 5 + 3] = bx.w;
                    sscore[r] = msc; slabel[r] = lab;
                }
            }
        }
        __syncthreads();
    }

    // ---- G: valid/maxc, class partition, IoU masks, chunked NMS, outputs ----
    float sc = (tid < KK) ? sscore[tid] : -1.0f;
    bool vq = (tid < KK) && (sc > CONF);
    u64 bm = __ballot(vq);
    if (lane == 0) validw[wv] = bm;
    float lm = vq ? fmaxf(fmaxf(sboxes[tid * 5 + 0], sboxes[tid * 5 + 1]),
                          fmaxf(sboxes[tid * 5 + 2], sboxes[tid * 5 + 3])) : 0.0f;
    for (int off = 32; off > 0; off >>= 1) lm = fmaxf(lm, __shfl_down(lm, off));
    if (lane == 0) wred[wv] = lm;
    __syncthreads();
    if (tid < 64) {
        float x = (tid < 8) ? wred[tid] : 0.0f;
        for (int off = 4; off > 0; off >>= 1) x = fmaxf(x, __shfl_down(x, off));
        if (tid == 0) s_maxc = x;
    }
    if (tid < 21) { ccnt[tid] = 0; cfill[tid] = 0; }
    if (tid < 8) sremv[tid] = 0ULL;
    __syncthreads();
    if (tid < KK) atomicAdd(&ccnt[slabel[tid]], 1);
    __syncthreads();
    if (tid == 0) {
        int acc = 0;
        for (int c = 0; c < 21; ++c) { coff[c] = acc; acc += ccnt[c]; }
        coff[21] = acc;
    }
    __syncthreads();
    if (tid < KK) {
        int c = slabel[tid];
        int pos = atomicAdd(&cfill[c], 1);
        clist[coff[c] + pos] = tid;
    }
    // overlay transposed masks msk[word][box] on pool (hist/pfx/tmp dead)
    u64 (*msk)[512] = (u64(*)[512])pool;      // 32 KB <= 37.9 KB
    for (int i = tid; i < 8 * 512; i += 512) ((u64*)pool)[i] = 0ULL;
    __syncthreads();

    float ap1 = s_maxc + 1.0f;
    if (tid < KK) {
        int c = slabel[tid];
        int n = ccnt[c], base0 = coff[c];
        float aoff = (float)c * ap1;
        float a0 = sboxes[tid * 5 + 0] + aoff, a1 = sboxes[tid * 5 + 1] + aoff;
        float a2 = sboxes[tid * 5 + 2] + aoff, a3 = sboxes[tid * 5 + 3] + aoff;
        float areaA = (a2 - a0) * (a3 - a1);
        for (int q = 0; q < n; ++q) {
            int j = clist[base0 + q];
            float b0 = sboxes[j * 5 + 0] + aoff, b1f = sboxes[j * 5 + 1] + aoff;
            float b2f = sboxes[j * 5 + 2] + aoff, b3f = sboxes[j * 5 + 3] + aoff;
            float lt0 = fmaxf(a0, b0), lt1 = fmaxf(a1, b1f);
            float rb0 = fminf(a2, b2f), rb1 = fminf(a3, b3f);
            float ww = fmaxf(rb0 - lt0, 0.0f), hh = fmaxf(rb1 - lt1, 0.0f);
            float inter = ww * hh;
            float areaB = (b2f - b0) * (b3f - b1f);
            float iou = inter / (areaA + areaB - inter);
            if (iou > NMSTHR) msk[j >> 6][tid] |= (1ULL << (j & 63));
        }
    }
    __syncthreads();

    // chunked greedy NMS: intra-chunk serial pass in registers (readlane),
    // cross-chunk suppression OR'd in parallel by waves c+1..7.
    for (int c = 0; c < 8; ++c) {
        if (wv == 0) {
            u64 rowc = msk[c][c * 64 + lane];   // row (c*64+lane), word c
            unsigned int rl = (unsigned int)rowc, rh = (unsigned int)(rowc >> 32);
            u64 cur = sremv[c];
            u64 vv = validw[c];
            u64 km = 0ULL;
            int nk = s_nk;
            for (int j = 0; j < 64; ++j) {
                if (nk >= KEEPN) break;
                bool alive = (((vv >> j) & 1ULL) != 0ULL) && (((cur >> j) & 1ULL) == 0ULL);
                if (alive) {
                    if (lane == 0) kept[nk] = c * 64 + j;
                    u64 rv = ((u64)(unsigned int)__builtin_amdgcn_readlane((int)rh, j) << 32)
                           |  (u64)(unsigned int)__builtin_amdgcn_readlane((int)rl, j);
                    cur |= rv;
                    km |= (1ULL << j);
                    ++nk;
                }
            }
            if (lane == 0) { s_km = km; s_nk = nk; sremv[c] = cur; s_stop = (nk >= KEEPN) ? 1 : 0; }
        }
        __syncthreads();
        if (s_stop || c == 7) break;
        if (wv > c) {
            u64 km = s_km;
            u64 v = ((km >> lane) & 1ULL) ? msk[wv][c * 64 + lane] : 0ULL;
            for (int off2 = 32; off2 > 0; off2 >>= 1) v |= __shfl_xor(v, off2);
            if (lane == 0) sremv[wv] |= v;
        }
        __syncthreads();
    }

    if (tid < KEEPN) {
        const int O_BOX = BB * KEEPN;
        const int O_LAB = BB * KEEPN * 5;
        const int O_SCO = BB * KEEPN * 6;
        const int O_VAL = BB * KEEPN * 7;
        bool q = tid < s_nk;
        int i = q ? kept[tid] : 0;
        int g = b * KEEPN + tid;
        out[g]                 = q ? (float)b : -1.0f;
        out[O_BOX + g * 4 + 0] = q ? sboxes[i * 5 + 0] : 0.0f;
        out[O_BOX + g * 4 + 1] = q ? sboxes[i * 5 + 1] : 0.0f;
        out[O_BOX + g * 4 + 2] = q ? sboxes[i * 5 + 2] : 0.0f;
        out[O_BOX + g * 4 + 3] = q ? sboxes[i * 5 + 3] : 0.0f;
        out[O_LAB + g]         = q ? (float)slabel[i] : -1.0f;
        out[O_SCO + g]         = q ? sscore[i] : 0.0f;
        out[O_VAL + g]         = q ? 1.0f : 0.0f;
    }
}

extern "C" void kernel_launch(void* const* d_in, const int* in_sizes, int n_in,
                              void* d_out, int out_size, void* d_ws, size_t ws_size,
                              hipStream_t stream) {
    const float* pscores = (const float*)d_in[0];
    const float* pboxes  = (const float*)d_in[1];
    const int*   plabels = (const int*)d_in[2];
    float* out = (float*)d_out;

    uint8_t* ws = (uint8_t*)d_ws;
    u64*          cand = (u64*)(ws + 0);
    unsigned int* cnts = (unsigned int*)(ws + 1179648);

    select_kernel<<<dim3(SLICES, BB), 1024, 0, stream>>>((const float4*)pscores, cand, cnts);
    final_kernel<<<BB, 512, 0, stream>>>(pboxes, plabels, cand, cnts, out);
}